// Round 1
// baseline (608.530 us; speedup 1.0000x reference)
//
#include <hip/hip_runtime.h>

// SwinStyleAttention fused kernel — MI355X gfx950, round 3.
// Block = 1 window (64 tok x 128 ch), 4 waves = 4 heads. All MFMA 16x16x32 bf16.
// R3 changes vs 605us baseline:
//  - Phase 0: channel-quad staging -> 8 ds_write_b64/thread (was 32 ds_write_b16),
//    identical XF layout and rounding.
//  - Barrier B3 removed (Os overlays the wave's OWN QFh region; same-wave order
//    is lgkmcnt-guaranteed; cross-wave XF reads all end before B2).
//  - log2(e) folded into Q pre-scale; softmax uses v_exp_f32 directly.
//  - s_setprio(1/0) around pure-MFMA clusters (T5; 3 independent blocks/CU).

typedef __attribute__((ext_vector_type(8))) short bf16x8;   // 8 bf16 = 4 VGPRs
typedef __attribute__((ext_vector_type(4))) float f32x4;    // 16x16 MFMA acc

// pack two floats -> dword of 2 bf16 (lo, hi), round-half-up (+0x8000)
__device__ __forceinline__ unsigned pk2(float lo, float hi) {
  union { float f; unsigned u; } a, b; a.f = lo; b.f = hi;
  return __builtin_amdgcn_perm(b.u + 0x8000u, a.u + 0x8000u, 0x07060302u);
}

__device__ __forceinline__ unsigned short f2bf_rne(float f) {
  union { float f; unsigned u; } v; v.f = f;
  return (unsigned short)((v.u + 0x7FFFu + ((v.u >> 16) & 1u)) >> 16);
}

// Weight prep: wqkvT[384][128] then wprojT[128][128], bf16, row n = out col.
__global__ void prep_kernel(const float* __restrict__ wqkv,
                            const float* __restrict__ wproj,
                            unsigned short* __restrict__ wT) {
  const int idx = blockIdx.x * 256 + (int)threadIdx.x;   // 65536 total
  if (idx < 384 * 128) {
    const int n = idx >> 7, k = idx & 127;
    wT[idx] = f2bf_rne(wqkv[k * 384 + n]);
  } else {
    const int j = idx - 384 * 128;
    const int n = j >> 7, k = j & 127;
    wT[idx] = f2bf_rne(wproj[k * 128 + n]);
  }
}

// LDS (shorts, 24576 = 48 KiB):
//  XF  [0,8192):     X frags [kc16][tok64][j8] -> per-head QF/P slots (wv*2048) -> Os
//  KB  [8192,16384): per-head KF [kc4][tok64][j8]
//  VB  [16384,24576): per-head VF [kcv8][dh32][j8]
__global__ void __launch_bounds__(256, 3)
swin_kernel(const float* __restrict__ x, const unsigned short* __restrict__ wT,
            const float* __restrict__ bproj, float* __restrict__ out) {
  __shared__ unsigned short SM[24576];

  const int bid = blockIdx.x;
  const int win = (bid & 7) * 1024 + (bid >> 3);   // XCD swizzle: image per XCD
  const int b  = win >> 10;
  const int wy = (win >> 5) & 31;
  const int wx = win & 31;
  const int tid  = (int)threadIdx.x;
  const int lane = tid & 63;
  const int wv   = tid >> 6;        // wave id == head id
  const int q    = lane >> 4;       // quad
  const int l16  = lane & 15;
  const int qh   = q >> 1, ql = q & 1;

  unsigned short* XF  = SM;
  unsigned short* KFh = SM + 8192  + wv * 2048;
  unsigned short* VFh = SM + 16384 + wv * 2048;
  unsigned short* QFh = XF + wv * 2048;    // Q frags, later P half-swap

  // ---- Phase 0: gather shifted window -> XF frag layout ----
  // Thread owns channel quad (c0..c0+3) x token quad (t0..t0+3):
  // 8 float4 loads + 8 ds_write_b64 (same XF layout as before).
  {
    const int t4 = tid & 15;                     // token quad id
    const int a  = tid >> 4;                     // channel quad base
    const int ty = t4 >> 1, txb = (t4 & 1) << 2;
    const int hh = (wy * 8 + ty + 4) & 255;      // roll(-4)
    const int ww = (wx * 8 + txb + 4) & 255;     // mult of 4 -> no wrap in float4
    const float* src = x + ((b * 128) * 256 + hh) * 256 + ww;
    const int t0 = t4 << 2;
#pragma unroll
    for (int i = 0; i < 2; ++i) {
      const int c0 = a * 4 + i * 64;             // channel quad base, mult of 4
      const float4 v0 = *(const float4*)(src + (c0    ) * 65536);
      const float4 v1 = *(const float4*)(src + (c0 + 1) * 65536);
      const float4 v2 = *(const float4*)(src + (c0 + 2) * 65536);
      const float4 v3 = *(const float4*)(src + (c0 + 3) * 65536);
      unsigned short* p = &XF[(c0 >> 3) * 512 + t0 * 8 + (c0 & 7)];
      uint2 w;
      w.x = pk2(v0.x, v1.x); w.y = pk2(v2.x, v3.x);
      *(uint2*)(p + 0)  = w;                     // token t0
      w.x = pk2(v0.y, v1.y); w.y = pk2(v2.y, v3.y);
      *(uint2*)(p + 8)  = w;                     // token t0+1
      w.x = pk2(v0.z, v1.z); w.y = pk2(v2.z, v3.z);
      *(uint2*)(p + 16) = w;                     // token t0+2
      w.x = pk2(v0.w, v1.w); w.y = pk2(v2.w, v3.w);
      *(uint2*)(p + 24) = w;                     // token t0+3
    }
  }
  __syncthreads();   // B1

  // ---- Pass A: QT,KT = W^T X^T  (m=dh_local 2 tiles, n=tok 4 tiles, k=C) ----
  f32x4 aQT[2][4] = {}; f32x4 aKT[2][4] = {};
#pragma unroll
  for (int ks = 0; ks < 4; ++ks) {
    const int ko = ks * 32 + q * 8;
    bf16x8 xb[4];
#pragma unroll
    for (int nt = 0; nt < 4; ++nt)
      xb[nt] = *(const bf16x8*)&XF[(ks * 4 + q) * 512 + (nt * 16 + l16) * 8];
#pragma unroll
    for (int mA = 0; mA < 2; ++mA) {
      const int row = wv * 32 + mA * 16 + l16;
      const bf16x8 wq = *(const bf16x8*)&wT[row * 128 + ko];
      const bf16x8 wk = *(const bf16x8*)&wT[(128 + row) * 128 + ko];
      __builtin_amdgcn_s_setprio(1);
#pragma unroll
      for (int nt = 0; nt < 4; ++nt) {
        aQT[mA][nt] = __builtin_amdgcn_mfma_f32_16x16x32_bf16(wq, xb[nt], aQT[mA][nt], 0, 0, 0);
        aKT[mA][nt] = __builtin_amdgcn_mfma_f32_16x16x32_bf16(wk, xb[nt], aKT[mA][nt], 0, 0, 0);
      }
      __builtin_amdgcn_s_setprio(0);
    }
  }
  // stage KF (region fresh, own-wave): dh = 16mA+8qh+4ql+r -> kc=2mA+qh, j=4ql+r
#pragma unroll
  for (int mA = 0; mA < 2; ++mA)
#pragma unroll
    for (int nt = 0; nt < 4; ++nt) {
      uint2 w;
      w.x = pk2(aKT[mA][nt][0], aKT[mA][nt][1]);
      w.y = pk2(aKT[mA][nt][2], aKT[mA][nt][3]);
      *(uint2*)&KFh[(mA * 2 + qh) * 512 + (nt * 16 + l16) * 8 + ql * 4] = w;
    }

  // ---- Pass B: V = X Wv (m=tok 4 tiles, n=dh 2 tiles) ----
  f32x4 aV[4][2] = {};
#pragma unroll
  for (int ks = 0; ks < 4; ++ks) {
    const int ko = ks * 32 + q * 8;
    bf16x8 af[4];
#pragma unroll
    for (int mt = 0; mt < 4; ++mt)
      af[mt] = *(const bf16x8*)&XF[(ks * 4 + q) * 512 + (mt * 16 + l16) * 8];
#pragma unroll
    for (int nt = 0; nt < 2; ++nt) {
      const bf16x8 bv = *(const bf16x8*)&wT[(256 + wv * 32 + nt * 16 + l16) * 128 + ko];
      __builtin_amdgcn_s_setprio(1);
#pragma unroll
      for (int mt = 0; mt < 4; ++mt)
        aV[mt][nt] = __builtin_amdgcn_mfma_f32_16x16x32_bf16(af[mt], bv, aV[mt][nt], 0, 0, 0);
      __builtin_amdgcn_s_setprio(0);
    }
  }
  // stage VF: tok = 16mt+8qh+4ql+r -> kcv=2mt+qh, j=4ql+r; dh=16nt+l16
#pragma unroll
  for (int mt = 0; mt < 4; ++mt)
#pragma unroll
    for (int nt = 0; nt < 2; ++nt) {
      uint2 w;
      w.x = pk2(aV[mt][nt][0], aV[mt][nt][1]);
      w.y = pk2(aV[mt][nt][2], aV[mt][nt][3]);
      *(uint2*)&VFh[(mt * 2 + qh) * 256 + (nt * 16 + l16) * 8 + ql * 4] = w;
    }
  __syncthreads();   // B2: all XF reads done -> QF may overlay

  // stage QF (pre-scaled by dh^-0.5 * log2(e); softmax then uses exp2 directly)
  constexpr float SC = 0.17677669529663687f * 1.4426950408889634f;
#pragma unroll
  for (int mA = 0; mA < 2; ++mA)
#pragma unroll
    for (int nt = 0; nt < 4; ++nt) {
      uint2 w;
      w.x = pk2(aQT[mA][nt][0] * SC, aQT[mA][nt][1] * SC);
      w.y = pk2(aQT[mA][nt][2] * SC, aQT[mA][nt][3] * SC);
      *(uint2*)&QFh[(mA * 2 + qh) * 512 + (nt * 16 + l16) * 8 + ql * 4] = w;
    }

  // ---- S^T = K Q^T : A=K-frag, B=Q-frag, single K=32 step ----
  bf16x8 kf[4], qf[4];
#pragma unroll
  for (int t = 0; t < 4; ++t) {
    kf[t] = *(const bf16x8*)&KFh[q * 512 + (t * 16 + l16) * 8];
    qf[t] = *(const bf16x8*)&QFh[q * 512 + (t * 16 + l16) * 8];
  }
  f32x4 aS[4][4] = {};
  __builtin_amdgcn_s_setprio(1);
#pragma unroll
  for (int mt = 0; mt < 4; ++mt)
#pragma unroll
    for (int nt = 0; nt < 4; ++nt)
      aS[mt][nt] = __builtin_amdgcn_mfma_f32_16x16x32_bf16(kf[mt], qf[nt], aS[mt][nt], 0, 0, 0);
  __builtin_amdgcn_s_setprio(0);
  // lane holds S[tq=16nt+l16][tk=16mt+4q+r]

  // ---- softmax (base-2; no max-subtract; 1/sum deferred to epilogue) ----
#pragma unroll
  for (int mt = 0; mt < 4; ++mt)
#pragma unroll
    for (int nt = 0; nt < 4; ++nt)
#pragma unroll
      for (int r = 0; r < 4; ++r)
        aS[mt][nt][r] = __builtin_amdgcn_exp2f(aS[mt][nt][r]);
  float inv[4];
#pragma unroll
  for (int nt = 0; nt < 4; ++nt) {
    float s = 0.f;
#pragma unroll
    for (int mt = 0; mt < 4; ++mt)
#pragma unroll
      for (int r = 0; r < 4; ++r) s += aS[mt][nt][r];
    s += __shfl_xor(s, 16);
    s += __shfl_xor(s, 32);
    inv[nt] = 1.0f / s;
  }

  // ---- O^T = V^T P^T, tk in 2 halves; P half-swapped into dead Q slot ----
  f32x4 aOT[2][4] = {};
#pragma unroll
  for (int h = 0; h < 2; ++h) {
#pragma unroll
    for (int mh = 0; mh < 2; ++mh) {
      const int mt = h * 2 + mh;
#pragma unroll
      for (int nt = 0; nt < 4; ++nt) {
        uint2 w;
        w.x = pk2(aS[mt][nt][0], aS[mt][nt][1]);
        w.y = pk2(aS[mt][nt][2], aS[mt][nt][3]);
        *(uint2*)&QFh[(mh * 2 + qh) * 512 + (nt * 16 + l16) * 8 + ql * 4] = w;
      }
    }
    bf16x8 pf[4], vf[2];
#pragma unroll
    for (int t = 0; t < 4; ++t)
      pf[t] = *(const bf16x8*)&QFh[q * 512 + (t * 16 + l16) * 8];
#pragma unroll
    for (int nb = 0; nb < 2; ++nb)
      vf[nb] = *(const bf16x8*)&VFh[(h * 4 + q) * 256 + (nb * 16 + l16) * 8];
    __builtin_amdgcn_s_setprio(1);
#pragma unroll
    for (int mo = 0; mo < 2; ++mo)
#pragma unroll
      for (int np = 0; np < 4; ++np)
        aOT[mo][np] = __builtin_amdgcn_mfma_f32_16x16x32_bf16(vf[mo], pf[np], aOT[mo][np], 0, 0, 0);
    __builtin_amdgcn_s_setprio(0);
  }
  // (B3 removed: Os below writes only this wave's own XF region = QFh, whose
  //  last cross-wave readers finished before B2; same-wave order via lgkmcnt.)

  // ---- stage Os (normalized): c = wv*32+16mo+8qh+4ql+r, tok = 16np+l16 ----
#pragma unroll
  for (int mo = 0; mo < 2; ++mo)
#pragma unroll
    for (int np = 0; np < 4; ++np) {
      const float s = inv[np];
      uint2 w;
      w.x = pk2(aOT[mo][np][0] * s, aOT[mo][np][1] * s);
      w.y = pk2(aOT[mo][np][2] * s, aOT[mo][np][3] * s);
      *(uint2*)&XF[(wv * 4 + mo * 2 + qh) * 512 + (np * 16 + l16) * 8 + ql * 4] = w;
    }
  __syncthreads();   // B4

  // ---- proj: out = Os[64x128] @ wproj + b ----
  f32x4 aP[4][2] = {};
#pragma unroll
  for (int ks = 0; ks < 4; ++ks) {
    const int ko = ks * 32 + q * 8;
    bf16x8 af[4];
#pragma unroll
    for (int mt = 0; mt < 4; ++mt)
      af[mt] = *(const bf16x8*)&XF[(ks * 4 + q) * 512 + (mt * 16 + l16) * 8];
#pragma unroll
    for (int nt = 0; nt < 2; ++nt) {
      const bf16x8 bw = *(const bf16x8*)&wT[(384 + wv * 32 + nt * 16 + l16) * 128 + ko];
      __builtin_amdgcn_s_setprio(1);
#pragma unroll
      for (int mt = 0; mt < 4; ++mt)
        aP[mt][nt] = __builtin_amdgcn_mfma_f32_16x16x32_bf16(af[mt], bw, aP[mt][nt], 0, 0, 0);
      __builtin_amdgcn_s_setprio(0);
    }
  }
#pragma unroll
  for (int nt = 0; nt < 2; ++nt) {
    const int c = wv * 32 + nt * 16 + l16;
    const float bias = bproj[c];
#pragma unroll
    for (int mt = 0; mt < 4; ++mt) {
      const int tb  = mt * 16 + q * 4;        // 4 consecutive tokens, same h row
      const int ty  = tb >> 3;
      const int txb = tb & 7;
      const int hh  = (wy * 8 + ty + 4) & 255;   // inverse roll(+4)
      const int ww  = (wx * 8 + txb + 4) & 255;
      float4 v;
      v.x = aP[mt][nt][0] + bias;
      v.y = aP[mt][nt][1] + bias;
      v.z = aP[mt][nt][2] + bias;
      v.w = aP[mt][nt][3] + bias;
      *(float4*)(out + ((b * 128 + c) * 256 + hh) * 256 + ww) = v;
    }
  }
}

extern "C" void kernel_launch(void* const* d_in, const int* in_sizes, int n_in,
                              void* d_out, int out_size, void* d_ws, size_t ws_size,
                              hipStream_t stream) {
  const float* x     = (const float*)d_in[0];
  const float* wqkv  = (const float*)d_in[1];
  const float* wproj = (const float*)d_in[2];
  const float* bp    = (const float*)d_in[3];
  unsigned short* wT = (unsigned short*)d_ws;    // 65536 bf16 = 131072 B

  prep_kernel<<<256, 256, 0, stream>>>(wqkv, wproj, wT);
  swin_kernel<<<8192, 256, 0, stream>>>(x, wT, bp, (float*)d_out);
}

// Round 2
// 607.760 us; speedup vs baseline: 1.0013x; 1.0013x over previous
//
#include <hip/hip_runtime.h>

// SwinStyleAttention fused kernel — MI355X gfx950, round 4.
// Block = 1 window (64 tok x 128 ch), 4 waves = 4 heads. All MFMA 16x16x32 bf16.
// R4 changes vs 306us/dispatch (R3):
//  - LDS 48KB -> 32KB: KF and VF share one 4KB per-wave scratch slot (disjoint
//    lifetimes: KF staged+read-to-regs before VF staging; DS pipe in-order per
//    wave, overlapping addresses block compiler reordering).
//  - S/softmax/PV restructured into tk-halves: aS peak 64 -> 32 regs (partial
//    row-sums carried across halves; normalization already deferred).
//  - __launch_bounds__(256, 4): 4 blocks/CU (was 3) -> occupancy ~30% -> ~45%.

typedef __attribute__((ext_vector_type(8))) short bf16x8;   // 8 bf16 = 4 VGPRs
typedef __attribute__((ext_vector_type(4))) float f32x4;    // 16x16 MFMA acc

// pack two floats -> dword of 2 bf16 (lo, hi), round-half-up (+0x8000)
__device__ __forceinline__ unsigned pk2(float lo, float hi) {
  union { float f; unsigned u; } a, b; a.f = lo; b.f = hi;
  return __builtin_amdgcn_perm(b.u + 0x8000u, a.u + 0x8000u, 0x07060302u);
}

__device__ __forceinline__ unsigned short f2bf_rne(float f) {
  union { float f; unsigned u; } v; v.f = f;
  return (unsigned short)((v.u + 0x7FFFu + ((v.u >> 16) & 1u)) >> 16);
}

// Weight prep: wqkvT[384][128] then wprojT[128][128], bf16, row n = out col.
__global__ void prep_kernel(const float* __restrict__ wqkv,
                            const float* __restrict__ wproj,
                            unsigned short* __restrict__ wT) {
  const int idx = blockIdx.x * 256 + (int)threadIdx.x;   // 65536 total
  if (idx < 384 * 128) {
    const int n = idx >> 7, k = idx & 127;
    wT[idx] = f2bf_rne(wqkv[k * 384 + n]);
  } else {
    const int j = idx - 384 * 128;
    const int n = j >> 7, k = j & 127;
    wT[idx] = f2bf_rne(wproj[k * 128 + n]);
  }
}

// LDS (shorts, 16384 = 32 KiB):
//  XF  [0,8192):     X frags [kc16][tok64][j8] -> per-head QF/P slots (wv*2048) -> Os
//  SC  [8192,16384): per-head scratch, KF [kc4][tok64][j8] then VF [kcv8][dh32][j8]
__global__ void __launch_bounds__(256, 4)
swin_kernel(const float* __restrict__ x, const unsigned short* __restrict__ wT,
            const float* __restrict__ bproj, float* __restrict__ out) {
  __shared__ unsigned short SM[16384];

  const int bid = blockIdx.x;
  const int win = (bid & 7) * 1024 + (bid >> 3);   // XCD swizzle: image per XCD
  const int b  = win >> 10;
  const int wy = (win >> 5) & 31;
  const int wx = win & 31;
  const int tid  = (int)threadIdx.x;
  const int lane = tid & 63;
  const int wv   = tid >> 6;        // wave id == head id
  const int q    = lane >> 4;       // quad
  const int l16  = lane & 15;
  const int qh   = q >> 1, ql = q & 1;

  unsigned short* XF  = SM;
  unsigned short* SCh = SM + 8192 + wv * 2048;   // per-wave scratch: KF then VF
  unsigned short* QFh = XF + wv * 2048;          // Q frags, later P half-swap, Os

  // ---- Phase 0: gather shifted window -> XF frag layout ----
  // Thread owns channel quad (c0..c0+3) x token quad (t0..t0+3):
  // 8 float4 loads + 8 ds_write_b64.
  {
    const int t4 = tid & 15;                     // token quad id
    const int a  = tid >> 4;                     // channel quad base
    const int ty = t4 >> 1, txb = (t4 & 1) << 2;
    const int hh = (wy * 8 + ty + 4) & 255;      // roll(-4)
    const int ww = (wx * 8 + txb + 4) & 255;     // mult of 4 -> no wrap in float4
    const float* src = x + ((b * 128) * 256 + hh) * 256 + ww;
    const int t0 = t4 << 2;
#pragma unroll
    for (int i = 0; i < 2; ++i) {
      const int c0 = a * 4 + i * 64;             // channel quad base, mult of 4
      const float4 v0 = *(const float4*)(src + (c0    ) * 65536);
      const float4 v1 = *(const float4*)(src + (c0 + 1) * 65536);
      const float4 v2 = *(const float4*)(src + (c0 + 2) * 65536);
      const float4 v3 = *(const float4*)(src + (c0 + 3) * 65536);
      unsigned short* p = &XF[(c0 >> 3) * 512 + t0 * 8 + (c0 & 7)];
      uint2 w;
      w.x = pk2(v0.x, v1.x); w.y = pk2(v2.x, v3.x);
      *(uint2*)(p + 0)  = w;                     // token t0
      w.x = pk2(v0.y, v1.y); w.y = pk2(v2.y, v3.y);
      *(uint2*)(p + 8)  = w;                     // token t0+1
      w.x = pk2(v0.z, v1.z); w.y = pk2(v2.z, v3.z);
      *(uint2*)(p + 16) = w;                     // token t0+2
      w.x = pk2(v0.w, v1.w); w.y = pk2(v2.w, v3.w);
      *(uint2*)(p + 24) = w;                     // token t0+3
    }
  }
  __syncthreads();   // B1

  // ---- Pass A: QT,KT = W^T X^T  (m=dh_local 2 tiles, n=tok 4 tiles, k=C) ----
  f32x4 aQT[2][4] = {}; f32x4 aKT[2][4] = {};
#pragma unroll
  for (int ks = 0; ks < 4; ++ks) {
    const int ko = ks * 32 + q * 8;
    bf16x8 xb[4];
#pragma unroll
    for (int nt = 0; nt < 4; ++nt)
      xb[nt] = *(const bf16x8*)&XF[(ks * 4 + q) * 512 + (nt * 16 + l16) * 8];
#pragma unroll
    for (int mA = 0; mA < 2; ++mA) {
      const int row = wv * 32 + mA * 16 + l16;
      const bf16x8 wq = *(const bf16x8*)&wT[row * 128 + ko];
      const bf16x8 wk = *(const bf16x8*)&wT[(128 + row) * 128 + ko];
      __builtin_amdgcn_s_setprio(1);
#pragma unroll
      for (int nt = 0; nt < 4; ++nt) {
        aQT[mA][nt] = __builtin_amdgcn_mfma_f32_16x16x32_bf16(wq, xb[nt], aQT[mA][nt], 0, 0, 0);
        aKT[mA][nt] = __builtin_amdgcn_mfma_f32_16x16x32_bf16(wk, xb[nt], aKT[mA][nt], 0, 0, 0);
      }
      __builtin_amdgcn_s_setprio(0);
    }
  }
  // stage KF into scratch (own-wave, pre-B2): dh = 16mA+8qh+4ql+r -> kc=2mA+qh, j=4ql+r
#pragma unroll
  for (int mA = 0; mA < 2; ++mA)
#pragma unroll
    for (int nt = 0; nt < 4; ++nt) {
      uint2 w;
      w.x = pk2(aKT[mA][nt][0], aKT[mA][nt][1]);
      w.y = pk2(aKT[mA][nt][2], aKT[mA][nt][3]);
      *(uint2*)&SCh[(mA * 2 + qh) * 512 + (nt * 16 + l16) * 8 + ql * 4] = w;
    }
  // pull K frags to registers NOW so the scratch can be reused for VF
  bf16x8 kf[4];
#pragma unroll
  for (int t = 0; t < 4; ++t)
    kf[t] = *(const bf16x8*)&SCh[q * 512 + (t * 16 + l16) * 8];
  asm volatile("" ::: "memory");   // keep VF writes below the kf reads

  // ---- Pass B: V = X Wv (m=tok 4 tiles, n=dh 2 tiles) ----
  f32x4 aV[4][2] = {};
#pragma unroll
  for (int ks = 0; ks < 4; ++ks) {
    const int ko = ks * 32 + q * 8;
    bf16x8 af[4];
#pragma unroll
    for (int mt = 0; mt < 4; ++mt)
      af[mt] = *(const bf16x8*)&XF[(ks * 4 + q) * 512 + (mt * 16 + l16) * 8];
#pragma unroll
    for (int nt = 0; nt < 2; ++nt) {
      const bf16x8 bv = *(const bf16x8*)&wT[(256 + wv * 32 + nt * 16 + l16) * 128 + ko];
      __builtin_amdgcn_s_setprio(1);
#pragma unroll
      for (int mt = 0; mt < 4; ++mt)
        aV[mt][nt] = __builtin_amdgcn_mfma_f32_16x16x32_bf16(af[mt], bv, aV[mt][nt], 0, 0, 0);
      __builtin_amdgcn_s_setprio(0);
    }
  }
  // stage VF into the SAME scratch (kf already in regs; DS pipe in-order):
  // tok = 16mt+8qh+4ql+r -> kcv=2mt+qh, j=4ql+r; dh=16nt+l16
#pragma unroll
  for (int mt = 0; mt < 4; ++mt)
#pragma unroll
    for (int nt = 0; nt < 2; ++nt) {
      uint2 w;
      w.x = pk2(aV[mt][nt][0], aV[mt][nt][1]);
      w.y = pk2(aV[mt][nt][2], aV[mt][nt][3]);
      *(uint2*)&SCh[(mt * 2 + qh) * 256 + (nt * 16 + l16) * 8 + ql * 4] = w;
    }
  __syncthreads();   // B2: all XF reads done -> QF may overlay

  // stage QF (pre-scaled by dh^-0.5 * log2(e); softmax uses exp2 directly)
  constexpr float SC = 0.17677669529663687f * 1.4426950408889634f;
#pragma unroll
  for (int mA = 0; mA < 2; ++mA)
#pragma unroll
    for (int nt = 0; nt < 4; ++nt) {
      uint2 w;
      w.x = pk2(aQT[mA][nt][0] * SC, aQT[mA][nt][1] * SC);
      w.y = pk2(aQT[mA][nt][2] * SC, aQT[mA][nt][3] * SC);
      *(uint2*)&QFh[(mA * 2 + qh) * 512 + (nt * 16 + l16) * 8 + ql * 4] = w;
    }
  bf16x8 qf[4];
#pragma unroll
  for (int t = 0; t < 4; ++t)
    qf[t] = *(const bf16x8*)&QFh[q * 512 + (t * 16 + l16) * 8];

  // ---- S^T/softmax/PV in tk-halves: aS peak 32 regs instead of 64 ----
  // lane holds S[tq=16nt+l16][tk=16(2h+mh)+4q+r]; row sums accumulated per half,
  // normalization (1/sum) deferred to the Os epilogue as before.
  f32x4 aOT[2][4] = {};
  float sacc[4] = {0.f, 0.f, 0.f, 0.f};
#pragma unroll
  for (int h = 0; h < 2; ++h) {
    f32x4 aSh[2][4] = {};
    __builtin_amdgcn_s_setprio(1);
#pragma unroll
    for (int mh = 0; mh < 2; ++mh)
#pragma unroll
      for (int nt = 0; nt < 4; ++nt)
        aSh[mh][nt] = __builtin_amdgcn_mfma_f32_16x16x32_bf16(kf[h * 2 + mh], qf[nt], aSh[mh][nt], 0, 0, 0);
    __builtin_amdgcn_s_setprio(0);
#pragma unroll
    for (int mh = 0; mh < 2; ++mh)
#pragma unroll
      for (int nt = 0; nt < 4; ++nt) {
#pragma unroll
        for (int r = 0; r < 4; ++r)
          aSh[mh][nt][r] = __builtin_amdgcn_exp2f(aSh[mh][nt][r]);
        sacc[nt] += aSh[mh][nt][0] + aSh[mh][nt][1] + aSh[mh][nt][2] + aSh[mh][nt][3];
        uint2 w;
        w.x = pk2(aSh[mh][nt][0], aSh[mh][nt][1]);
        w.y = pk2(aSh[mh][nt][2], aSh[mh][nt][3]);
        *(uint2*)&QFh[(mh * 2 + qh) * 512 + (nt * 16 + l16) * 8 + ql * 4] = w;
      }
    bf16x8 pf[4], vf[2];
#pragma unroll
    for (int t = 0; t < 4; ++t)
      pf[t] = *(const bf16x8*)&QFh[q * 512 + (t * 16 + l16) * 8];
#pragma unroll
    for (int nb = 0; nb < 2; ++nb)
      vf[nb] = *(const bf16x8*)&SCh[(h * 4 + q) * 256 + (nb * 16 + l16) * 8];
    __builtin_amdgcn_s_setprio(1);
#pragma unroll
    for (int mo = 0; mo < 2; ++mo)
#pragma unroll
      for (int np = 0; np < 4; ++np)
        aOT[mo][np] = __builtin_amdgcn_mfma_f32_16x16x32_bf16(vf[mo], pf[np], aOT[mo][np], 0, 0, 0);
    __builtin_amdgcn_s_setprio(0);
  }
  float inv[4];
#pragma unroll
  for (int nt = 0; nt < 4; ++nt) {
    float s = sacc[nt];
    s += __shfl_xor(s, 16);
    s += __shfl_xor(s, 32);
    inv[nt] = 1.0f / s;
  }

  // ---- stage Os (normalized): c = wv*32+16mo+8qh+4ql+r, tok = 16np+l16 ----
#pragma unroll
  for (int mo = 0; mo < 2; ++mo)
#pragma unroll
    for (int np = 0; np < 4; ++np) {
      const float s = inv[np];
      uint2 w;
      w.x = pk2(aOT[mo][np][0] * s, aOT[mo][np][1] * s);
      w.y = pk2(aOT[mo][np][2] * s, aOT[mo][np][3] * s);
      *(uint2*)&XF[(wv * 4 + mo * 2 + qh) * 512 + (np * 16 + l16) * 8 + ql * 4] = w;
    }
  __syncthreads();   // B4

  // ---- proj: out = Os[64x128] @ wproj + b ----
  f32x4 aP[4][2] = {};
#pragma unroll
  for (int ks = 0; ks < 4; ++ks) {
    const int ko = ks * 32 + q * 8;
    bf16x8 af[4];
#pragma unroll
    for (int mt = 0; mt < 4; ++mt)
      af[mt] = *(const bf16x8*)&XF[(ks * 4 + q) * 512 + (mt * 16 + l16) * 8];
#pragma unroll
    for (int nt = 0; nt < 2; ++nt) {
      const bf16x8 bw = *(const bf16x8*)&wT[(384 + wv * 32 + nt * 16 + l16) * 128 + ko];
      __builtin_amdgcn_s_setprio(1);
#pragma unroll
      for (int mt = 0; mt < 4; ++mt)
        aP[mt][nt] = __builtin_amdgcn_mfma_f32_16x16x32_bf16(af[mt], bw, aP[mt][nt], 0, 0, 0);
      __builtin_amdgcn_s_setprio(0);
    }
  }
#pragma unroll
  for (int nt = 0; nt < 2; ++nt) {
    const int c = wv * 32 + nt * 16 + l16;
    const float bias = bproj[c];
#pragma unroll
    for (int mt = 0; mt < 4; ++mt) {
      const int tb  = mt * 16 + q * 4;        // 4 consecutive tokens, same h row
      const int ty  = tb >> 3;
      const int txb = tb & 7;
      const int hh  = (wy * 8 + ty + 4) & 255;   // inverse roll(+4)
      const int ww  = (wx * 8 + txb + 4) & 255;
      float4 v;
      v.x = aP[mt][nt][0] + bias;
      v.y = aP[mt][nt][1] + bias;
      v.z = aP[mt][nt][2] + bias;
      v.w = aP[mt][nt][3] + bias;
      *(float4*)(out + ((b * 128 + c) * 256 + hh) * 256 + ww) = v;
    }
  }
}

extern "C" void kernel_launch(void* const* d_in, const int* in_sizes, int n_in,
                              void* d_out, int out_size, void* d_ws, size_t ws_size,
                              hipStream_t stream) {
  const float* x     = (const float*)d_in[0];
  const float* wqkv  = (const float*)d_in[1];
  const float* wproj = (const float*)d_in[2];
  const float* bp    = (const float*)d_in[3];
  unsigned short* wT = (unsigned short*)d_ws;    // 65536 bf16 = 131072 B

  prep_kernel<<<256, 256, 0, stream>>>(wqkv, wproj, wT);
  swin_kernel<<<8192, 256, 0, stream>>>(x, wT, bp, (float*)d_out);
}

// Round 3
// 602.441 us; speedup vs baseline: 1.0101x; 1.0088x over previous
//
#include <hip/hip_runtime.h>

// SwinStyleAttention fused kernel — MI355X gfx950, round 5.
// Block = 1 window (64 tok x 128 ch), 4 waves = 4 heads. All MFMA 16x16x32 bf16.
// R5 changes vs 300us/dispatch (R4):
//  - Fused QKV pass: one xb[4] LDS read per ks feeds Q^T,K^T (B-op) AND V (A-op)
//    (Pass B previously re-read identical XF addresses) -> -16 ds_read_b128/wave.
//  - ks=0 QKV weights preloaded BEFORE B1; proj ks=0 weights preloaded before
//    the softmax/PV phase (barriers fence loads; manual hoist hides L2 latency).
//  - QF gets its own LDS region (48KB total): no barrier between XF reads and
//    QF staging; the XF-protection barrier moves to after PV (skew absorbed by
//    independent register work). Still 3 barriers, much better placement.
//  - 3 blocks/CU (reg pressure from live Q/K/V accs); R2 showed 3<->4 ~ neutral.

typedef __attribute__((ext_vector_type(8))) short bf16x8;   // 8 bf16 = 4 VGPRs
typedef __attribute__((ext_vector_type(4))) float f32x4;    // 16x16 MFMA acc

// pack two floats -> dword of 2 bf16 (lo, hi), round-half-up (+0x8000)
__device__ __forceinline__ unsigned pk2(float lo, float hi) {
  union { float f; unsigned u; } a, b; a.f = lo; b.f = hi;
  return __builtin_amdgcn_perm(b.u + 0x8000u, a.u + 0x8000u, 0x07060302u);
}

__device__ __forceinline__ unsigned short f2bf_rne(float f) {
  union { float f; unsigned u; } v; v.f = f;
  return (unsigned short)((v.u + 0x7FFFu + ((v.u >> 16) & 1u)) >> 16);
}

// Weight prep: wqkvT[384][128] then wprojT[128][128], bf16, row n = out col.
__global__ void prep_kernel(const float* __restrict__ wqkv,
                            const float* __restrict__ wproj,
                            unsigned short* __restrict__ wT) {
  const int idx = blockIdx.x * 256 + (int)threadIdx.x;   // 65536 total
  if (idx < 384 * 128) {
    const int n = idx >> 7, k = idx & 127;
    wT[idx] = f2bf_rne(wqkv[k * 384 + n]);
  } else {
    const int j = idx - 384 * 128;
    const int n = j >> 7, k = j & 127;
    wT[idx] = f2bf_rne(wproj[k * 128 + n]);
  }
}

// LDS (shorts, 24576 = 48 KiB):
//  XF  [0,8192):      X frags [kc16][tok64][j8] -> later Os frags
//  SC  [8192,16384):  per-head scratch, KF [kc4][tok64][j8] then VF [kcv8][dh32][j8]
//  QF  [16384,24576): per-head Q frags [kc4][tok64][j8], later P half-swap
__global__ void __launch_bounds__(256, 3)
swin_kernel(const float* __restrict__ x, const unsigned short* __restrict__ wT,
            const float* __restrict__ bproj, float* __restrict__ out) {
  __shared__ unsigned short SM[24576];

  const int bid = blockIdx.x;
  const int win = (bid & 7) * 1024 + (bid >> 3);   // XCD swizzle: image per XCD
  const int b  = win >> 10;
  const int wy = (win >> 5) & 31;
  const int wx = win & 31;
  const int tid  = (int)threadIdx.x;
  const int lane = tid & 63;
  const int wv   = tid >> 6;        // wave id == head id
  const int q    = lane >> 4;       // quad
  const int l16  = lane & 15;
  const int qh   = q >> 1, ql = q & 1;

  unsigned short* XF  = SM;
  unsigned short* SCh = SM + 8192  + wv * 2048;   // per-wave scratch: KF then VF
  unsigned short* QFh = SM + 16384 + wv * 2048;   // per-wave: QF then P

  // ---- Phase 0: gather shifted window -> XF frag layout ----
  // Thread owns channel quad (c0..c0+3) x token quad (t0..t0+3):
  // 8 float4 loads + 8 ds_write_b64.
  {
    const int t4 = tid & 15;                     // token quad id
    const int a  = tid >> 4;                     // channel quad base
    const int ty = t4 >> 1, txb = (t4 & 1) << 2;
    const int hh = (wy * 8 + ty + 4) & 255;      // roll(-4)
    const int ww = (wx * 8 + txb + 4) & 255;     // mult of 4 -> no wrap in float4
    const float* src = x + ((b * 128) * 256 + hh) * 256 + ww;
    const int t0 = t4 << 2;
#pragma unroll
    for (int i = 0; i < 2; ++i) {
      const int c0 = a * 4 + i * 64;             // channel quad base, mult of 4
      const float4 v0 = *(const float4*)(src + (c0    ) * 65536);
      const float4 v1 = *(const float4*)(src + (c0 + 1) * 65536);
      const float4 v2 = *(const float4*)(src + (c0 + 2) * 65536);
      const float4 v3 = *(const float4*)(src + (c0 + 3) * 65536);
      unsigned short* p = &XF[(c0 >> 3) * 512 + t0 * 8 + (c0 & 7)];
      uint2 w;
      w.x = pk2(v0.x, v1.x); w.y = pk2(v2.x, v3.x);
      *(uint2*)(p + 0)  = w;                     // token t0
      w.x = pk2(v0.y, v1.y); w.y = pk2(v2.y, v3.y);
      *(uint2*)(p + 8)  = w;                     // token t0+1
      w.x = pk2(v0.z, v1.z); w.y = pk2(v2.z, v3.z);
      *(uint2*)(p + 16) = w;                     // token t0+2
      w.x = pk2(v0.w, v1.w); w.y = pk2(v2.w, v3.w);
      *(uint2*)(p + 24) = w;                     // token t0+3
    }
  }

  // preload ks=0 QKV weight frags BEFORE the barrier (loads can't cross it)
  bf16x8 wq0[2], wk0[2], bv0[2];
  {
    const int ko0 = q * 8;
#pragma unroll
    for (int mA = 0; mA < 2; ++mA) {
      const int row = wv * 32 + mA * 16 + l16;
      wq0[mA] = *(const bf16x8*)&wT[row * 128 + ko0];
      wk0[mA] = *(const bf16x8*)&wT[(128 + row) * 128 + ko0];
    }
#pragma unroll
    for (int nt = 0; nt < 2; ++nt)
      bv0[nt] = *(const bf16x8*)&wT[(256 + wv * 32 + nt * 16 + l16) * 128 + ko0];
  }
  __syncthreads();   // B1

  // ---- Fused QKV pass: QT,KT = W^T X^T and V = X Wv off ONE xb[4] read/ks ----
  f32x4 aQT[2][4] = {}; f32x4 aKT[2][4] = {}; f32x4 aV[4][2] = {};
#pragma unroll
  for (int ks = 0; ks < 4; ++ks) {
    const int ko = ks * 32 + q * 8;
    bf16x8 xb[4];
#pragma unroll
    for (int nt = 0; nt < 4; ++nt)
      xb[nt] = *(const bf16x8*)&XF[(ks * 4 + q) * 512 + (nt * 16 + l16) * 8];
    bf16x8 wq[2], wk[2], bv[2];
    if (ks == 0) {
      wq[0] = wq0[0]; wq[1] = wq0[1];
      wk[0] = wk0[0]; wk[1] = wk0[1];
      bv[0] = bv0[0]; bv[1] = bv0[1];
    } else {
#pragma unroll
      for (int mA = 0; mA < 2; ++mA) {
        const int row = wv * 32 + mA * 16 + l16;
        wq[mA] = *(const bf16x8*)&wT[row * 128 + ko];
        wk[mA] = *(const bf16x8*)&wT[(128 + row) * 128 + ko];
      }
#pragma unroll
      for (int nt = 0; nt < 2; ++nt)
        bv[nt] = *(const bf16x8*)&wT[(256 + wv * 32 + nt * 16 + l16) * 128 + ko];
    }
#pragma unroll
    for (int mA = 0; mA < 2; ++mA) {
      __builtin_amdgcn_s_setprio(1);
#pragma unroll
      for (int nt = 0; nt < 4; ++nt) {
        aQT[mA][nt] = __builtin_amdgcn_mfma_f32_16x16x32_bf16(wq[mA], xb[nt], aQT[mA][nt], 0, 0, 0);
        aKT[mA][nt] = __builtin_amdgcn_mfma_f32_16x16x32_bf16(wk[mA], xb[nt], aKT[mA][nt], 0, 0, 0);
      }
      __builtin_amdgcn_s_setprio(0);
    }
#pragma unroll
    for (int nt = 0; nt < 2; ++nt) {
      __builtin_amdgcn_s_setprio(1);
#pragma unroll
      for (int mt = 0; mt < 4; ++mt)
        aV[mt][nt] = __builtin_amdgcn_mfma_f32_16x16x32_bf16(xb[mt], bv[nt], aV[mt][nt], 0, 0, 0);
      __builtin_amdgcn_s_setprio(0);
    }
  }

  // stage KF into scratch: dh = 16mA+8qh+4ql+r -> kc=2mA+qh, j=4ql+r
#pragma unroll
  for (int mA = 0; mA < 2; ++mA)
#pragma unroll
    for (int nt = 0; nt < 4; ++nt) {
      uint2 w;
      w.x = pk2(aKT[mA][nt][0], aKT[mA][nt][1]);
      w.y = pk2(aKT[mA][nt][2], aKT[mA][nt][3]);
      *(uint2*)&SCh[(mA * 2 + qh) * 512 + (nt * 16 + l16) * 8 + ql * 4] = w;
    }
  // pull K frags to registers NOW so the scratch can be reused for VF
  bf16x8 kf[4];
#pragma unroll
  for (int t = 0; t < 4; ++t)
    kf[t] = *(const bf16x8*)&SCh[q * 512 + (t * 16 + l16) * 8];
  asm volatile("" ::: "memory");   // keep VF writes below the kf reads

  // stage VF into the SAME scratch (kf in regs; DS pipe in-order per wave):
  // tok = 16mt+8qh+4ql+r -> kcv=2mt+qh, j=4ql+r; dh=16nt+l16
#pragma unroll
  for (int mt = 0; mt < 4; ++mt)
#pragma unroll
    for (int nt = 0; nt < 2; ++nt) {
      uint2 w;
      w.x = pk2(aV[mt][nt][0], aV[mt][nt][1]);
      w.y = pk2(aV[mt][nt][2], aV[mt][nt][3]);
      *(uint2*)&SCh[(mt * 2 + qh) * 256 + (nt * 16 + l16) * 8 + ql * 4] = w;
    }

  // stage QF into own region (no barrier needed: own-wave write->read, in-order)
  // pre-scaled by dh^-0.5 * log2(e); softmax uses exp2 directly
  constexpr float SC = 0.17677669529663687f * 1.4426950408889634f;
#pragma unroll
  for (int mA = 0; mA < 2; ++mA)
#pragma unroll
    for (int nt = 0; nt < 4; ++nt) {
      uint2 w;
      w.x = pk2(aQT[mA][nt][0] * SC, aQT[mA][nt][1] * SC);
      w.y = pk2(aQT[mA][nt][2] * SC, aQT[mA][nt][3] * SC);
      *(uint2*)&QFh[(mA * 2 + qh) * 512 + (nt * 16 + l16) * 8 + ql * 4] = w;
    }
  bf16x8 qf[4];
#pragma unroll
  for (int t = 0; t < 4; ++t)
    qf[t] = *(const bf16x8*)&QFh[q * 512 + (t * 16 + l16) * 8];

  // preload proj ks=0 weight frags; ~2K cycles of softmax/PV below hides L2 lat
  bf16x8 bw0[2];
#pragma unroll
  for (int nt = 0; nt < 2; ++nt)
    bw0[nt] = *(const bf16x8*)&wT[(384 + wv * 32 + nt * 16 + l16) * 128 + q * 8];

  // ---- S^T/softmax/PV in tk-halves ----
  // lane holds S[tq=16nt+l16][tk=16(2h+mh)+4q+r]; row sums accumulated per half,
  // normalization (1/sum) deferred to the Os epilogue.
  f32x4 aOT[2][4] = {};
  float sacc[4] = {0.f, 0.f, 0.f, 0.f};
#pragma unroll
  for (int h = 0; h < 2; ++h) {
    f32x4 aSh[2][4] = {};
    __builtin_amdgcn_s_setprio(1);
#pragma unroll
    for (int mh = 0; mh < 2; ++mh)
#pragma unroll
      for (int nt = 0; nt < 4; ++nt)
        aSh[mh][nt] = __builtin_amdgcn_mfma_f32_16x16x32_bf16(kf[h * 2 + mh], qf[nt], aSh[mh][nt], 0, 0, 0);
    __builtin_amdgcn_s_setprio(0);
#pragma unroll
    for (int mh = 0; mh < 2; ++mh)
#pragma unroll
      for (int nt = 0; nt < 4; ++nt) {
#pragma unroll
        for (int r = 0; r < 4; ++r)
          aSh[mh][nt][r] = __builtin_amdgcn_exp2f(aSh[mh][nt][r]);
        sacc[nt] += aSh[mh][nt][0] + aSh[mh][nt][1] + aSh[mh][nt][2] + aSh[mh][nt][3];
        uint2 w;
        w.x = pk2(aSh[mh][nt][0], aSh[mh][nt][1]);
        w.y = pk2(aSh[mh][nt][2], aSh[mh][nt][3]);
        *(uint2*)&QFh[(mh * 2 + qh) * 512 + (nt * 16 + l16) * 8 + ql * 4] = w;
      }
    bf16x8 pf[4], vf[2];
#pragma unroll
    for (int t = 0; t < 4; ++t)
      pf[t] = *(const bf16x8*)&QFh[q * 512 + (t * 16 + l16) * 8];
#pragma unroll
    for (int nb = 0; nb < 2; ++nb)
      vf[nb] = *(const bf16x8*)&SCh[(h * 4 + q) * 256 + (nb * 16 + l16) * 8];
    __builtin_amdgcn_s_setprio(1);
#pragma unroll
    for (int mo = 0; mo < 2; ++mo)
#pragma unroll
      for (int np = 0; np < 4; ++np)
        aOT[mo][np] = __builtin_amdgcn_mfma_f32_16x16x32_bf16(vf[mo], pf[np], aOT[mo][np], 0, 0, 0);
    __builtin_amdgcn_s_setprio(0);
  }
  float inv[4];
#pragma unroll
  for (int nt = 0; nt < 4; ++nt) {
    float s = sacc[nt];
    s += __shfl_xor(s, 16);
    s += __shfl_xor(s, 32);
    inv[nt] = 1.0f / s;
  }

  __syncthreads();   // B_preOs: all waves' XF reads done -> Os may overlay XF

  // ---- stage Os (normalized): c = wv*32+16mo+8qh+4ql+r, tok = 16np+l16 ----
#pragma unroll
  for (int mo = 0; mo < 2; ++mo)
#pragma unroll
    for (int np = 0; np < 4; ++np) {
      const float s = inv[np];
      uint2 w;
      w.x = pk2(aOT[mo][np][0] * s, aOT[mo][np][1] * s);
      w.y = pk2(aOT[mo][np][2] * s, aOT[mo][np][3] * s);
      *(uint2*)&XF[(wv * 4 + mo * 2 + qh) * 512 + (np * 16 + l16) * 8 + ql * 4] = w;
    }
  __syncthreads();   // B4

  // ---- proj: out = Os[64x128] @ wproj + b ----
  f32x4 aP[4][2] = {};
#pragma unroll
  for (int ks = 0; ks < 4; ++ks) {
    const int ko = ks * 32 + q * 8;
    bf16x8 af[4];
#pragma unroll
    for (int mt = 0; mt < 4; ++mt)
      af[mt] = *(const bf16x8*)&XF[(ks * 4 + q) * 512 + (mt * 16 + l16) * 8];
#pragma unroll
    for (int nt = 0; nt < 2; ++nt) {
      bf16x8 bw;
      if (ks == 0) bw = bw0[nt];
      else bw = *(const bf16x8*)&wT[(384 + wv * 32 + nt * 16 + l16) * 128 + ko];
      __builtin_amdgcn_s_setprio(1);
#pragma unroll
      for (int mt = 0; mt < 4; ++mt)
        aP[mt][nt] = __builtin_amdgcn_mfma_f32_16x16x32_bf16(af[mt], bw, aP[mt][nt], 0, 0, 0);
      __builtin_amdgcn_s_setprio(0);
    }
  }
#pragma unroll
  for (int nt = 0; nt < 2; ++nt) {
    const int c = wv * 32 + nt * 16 + l16;
    const float bias = bproj[c];
#pragma unroll
    for (int mt = 0; mt < 4; ++mt) {
      const int tb  = mt * 16 + q * 4;        // 4 consecutive tokens, same h row
      const int ty  = tb >> 3;
      const int txb = tb & 7;
      const int hh  = (wy * 8 + ty + 4) & 255;   // inverse roll(+4)
      const int ww  = (wx * 8 + txb + 4) & 255;
      float4 v;
      v.x = aP[mt][nt][0] + bias;
      v.y = aP[mt][nt][1] + bias;
      v.z = aP[mt][nt][2] + bias;
      v.w = aP[mt][nt][3] + bias;
      *(float4*)(out + ((b * 128 + c) * 256 + hh) * 256 + ww) = v;
    }
  }
}

extern "C" void kernel_launch(void* const* d_in, const int* in_sizes, int n_in,
                              void* d_out, int out_size, void* d_ws, size_t ws_size,
                              hipStream_t stream) {
  const float* x     = (const float*)d_in[0];
  const float* wqkv  = (const float*)d_in[1];
  const float* wproj = (const float*)d_in[2];
  const float* bp    = (const float*)d_in[3];
  unsigned short* wT = (unsigned short*)d_ws;    // 65536 bf16 = 131072 B

  prep_kernel<<<256, 256, 0, stream>>>(wqkv, wproj, wT);
  swin_kernel<<<8192, 256, 0, stream>>>(x, wT, bp, (float*)d_out);
}